// Round 1
// baseline (157.577 us; speedup 1.0000x reference)
//
#include <hip/hip_runtime.h>

// ChannelAttention fused kernel for MI355X (gfx950), round 5.
// B=4, L=16384, C=128, H=8, hd=16. Tokens M = 65536.
//
// R5 changes vs R4 (occupancy was LDS-capped at 3 blocks/CU = 37.5%):
//   - Half-tile LDS pipeline: stage A still computes all 32 tokens' qkv in
//     registers (acc[2][6]), but the fp32 transpose buffer now holds only
//     16 tokens (16x388x4 = 24832 B) and is reused for the second half.
//     Separate 16-token o buffer (4352 B). LDS 29184 B -> 5 blocks/CU,
//     occupancy cap 37.5% -> 62.5%.
//   - Stage B re-split so all 256 threads work on 16 tokens: thread =
//     (t, h, i-half); 8x16 exp2 per call, 10x ds_read_b128.
//   - Half-1 qkv LDS writes overlap stage-C-half-0 (weights + MFMA) in the
//     same barrier interval. 4 barriers total.
//   - __launch_bounds__(256,5) so the register allocator targets 5 blocks/CU.
// Math path identical to R4 (fp32 LDS, bf16 MFMA operands, exp2 softmax).

typedef __attribute__((ext_vector_type(8))) short bf16x8;
typedef __attribute__((ext_vector_type(4))) float f32x4;
typedef __attribute__((ext_vector_type(4))) unsigned int u32x4;

#define TILE_M 32
#define HALF_M 16
#define QKV_STRIDE_F 388   // fp32 elems per token row (>=384; %8==4 -> 16B aligned rows, spread banks)
#define O_STRIDE 136       // bf16 elems per o row

__device__ __forceinline__ unsigned short f2bf(float f) {
    unsigned int u = __builtin_bit_cast(unsigned int, f);
    u += 0x8000u;                      // round half up (cheap, <=0.5 ulp + tie bias)
    return (unsigned short)(u >> 16);
}
// pack two floats -> packed bf16x2 (lo in low short) in 3 VALU ops
__device__ __forceinline__ unsigned int pkbf(float lo, float hi) {
    unsigned int a = __builtin_bit_cast(unsigned int, lo) + 0x8000u;
    unsigned int b = __builtin_bit_cast(unsigned int, hi) + 0x8000u;
    return __builtin_amdgcn_perm(b, a, 0x07060302u);  // {hi16(b),hi16(a)}
}

__global__ void prep_weights(const float* __restrict__ wqkv,
                             const float* __restrict__ wproj,
                             unsigned short* __restrict__ wqkvT,
                             unsigned short* __restrict__ wprojT) {
    int idx = blockIdx.x * 256 + threadIdx.x;
    if (idx < 384 * 128) {               // wqkvT[n][k] = bf16(wqkv[k][n])
        int n = idx >> 7, k = idx & 127;
        wqkvT[idx] = f2bf(wqkv[k * 384 + n]);
    }
    if (idx < 128 * 128) {               // wprojT[n][k] = bf16(wproj[k][n])
        int n = idx >> 7, k = idx & 127;
        wprojT[idx] = f2bf(wproj[k * 128 + n]);
    }
}

__global__ __launch_bounds__(256, 5) void fused_channel_attn(
    const float* __restrict__ x,
    const unsigned short* __restrict__ wqkvT,
    const float* __restrict__ bqkv,
    const unsigned short* __restrict__ wprojT,
    const float* __restrict__ bproj,
    float* __restrict__ out)
{
    __shared__ __align__(16) float us_f[HALF_M * QKV_STRIDE_F];        // 24832 B, half-tile qkv fp32
    __shared__ __align__(16) unsigned short us_o[HALF_M * O_STRIDE];   // 4352 B, half-tile o bf16

    const int tid  = threadIdx.x;
    const int lane = tid & 63;
    const int wave = tid >> 6;
    const int col  = lane & 15;   // MFMA C/D col == A row (m) == B col (n)
    const int quad = lane >> 4;
    const long base_tok = (long)blockIdx.x * TILE_M;

    const int nb = wave * 6;      // this wave's 6 qkv n-tiles (both m-tiles)

    // ---- stage A: x fragments for both m-tiles, 16 loads in flight
    float4 xf[2][4][2];
#pragma unroll
    for (int m = 0; m < 2; ++m) {
        const float* xrow = x + (base_tok + m * 16 + col) * 128;
#pragma unroll
        for (int ks = 0; ks < 4; ++ks) {
            const float4* p = (const float4*)(xrow + ks * 32 + quad * 8);
            xf[m][ks][0] = p[0];
            xf[m][ks][1] = p[1];
        }
    }
    bf16x8 afr[2][4];
#pragma unroll
    for (int m = 0; m < 2; ++m)
#pragma unroll
        for (int ks = 0; ks < 4; ++ks) {
            float4 f0 = xf[m][ks][0], f1 = xf[m][ks][1];
            u32x4 a = {pkbf(f0.x, f0.y), pkbf(f0.z, f0.w),
                       pkbf(f1.x, f1.y), pkbf(f1.z, f1.w)};
            afr[m][ks] = __builtin_bit_cast(bf16x8, a);
        }

    // acc[m][j][r] = qkv[m*16 + quad*4 + r][(nb+j)*16 + col]; init = bias
    f32x4 acc[2][6];
#pragma unroll
    for (int j = 0; j < 6; ++j) {
        float b = bqkv[(nb + j) * 16 + col];
        acc[0][j] = (f32x4){b, b, b, b};
        acc[1][j] = (f32x4){b, b, b, b};
    }
#pragma unroll
    for (int ks = 0; ks < 4; ++ks) {
        bf16x8 bfr[6];                 // batched: 6 loads in flight
#pragma unroll
        for (int j = 0; j < 6; ++j)
            bfr[j] = *(const bf16x8*)&wqkvT[((nb + j) * 16 + col) * 128 + ks * 32 + quad * 8];
#pragma unroll
        for (int j = 0; j < 6; ++j) {  // each bfrag feeds 2 MFMAs
            acc[0][j] = __builtin_amdgcn_mfma_f32_16x16x32_bf16(afr[0][ks], bfr[j], acc[0][j], 0, 0, 0);
            acc[1][j] = __builtin_amdgcn_mfma_f32_16x16x32_bf16(afr[1][ks], bfr[j], acc[1][j], 0, 0, 0);
        }
    }

    // ---- stage B thread mapping: 16 tokens x 8 heads x 2 i-halves = 256
    const int t  = tid & 15;
    const int h  = (tid >> 4) & 7;
    const int ih = tid >> 7;
    const float sl2e = 0.08838834764831845f * 1.44269504088896340f; // scale*log2(e)

    // write one 16-token half of qkv -> LDS fp32 [tok][ch]
    auto write_qkv_half = [&](int m) {
#pragma unroll
        for (int j = 0; j < 6; ++j)
#pragma unroll
            for (int r = 0; r < 4; ++r)
                us_f[(quad * 4 + r) * QKV_STRIDE_F + (nb + j) * 16 + col] = acc[m][j][r];
    };

    // per-token-head channel attention on the current LDS half-tile
    auto stage_b_half = [&]() {
        const float* qkvrow = us_f + t * QKV_STRIDE_F + h * 16;
        float4 qv4[2], kv4[4], vv4[4];   // 10 ds_read_b128
        qv4[0] = ((const float4*)(qkvrow + ih * 8))[0];
        qv4[1] = ((const float4*)(qkvrow + ih * 8))[1];
#pragma unroll
        for (int c = 0; c < 4; ++c) {
            kv4[c] = ((const float4*)(qkvrow + 128))[c];
            vv4[c] = ((const float4*)(qkvrow + 256))[c];
        }
        float qv[8], kf[16], vf[16];
#pragma unroll
        for (int c = 0; c < 2; ++c) {
            qv[4*c] = qv4[c].x; qv[4*c+1] = qv4[c].y; qv[4*c+2] = qv4[c].z; qv[4*c+3] = qv4[c].w;
        }
#pragma unroll
        for (int c = 0; c < 4; ++c) {
            kf[4*c] = kv4[c].x; kf[4*c+1] = kv4[c].y; kf[4*c+2] = kv4[c].z; kf[4*c+3] = kv4[c].w;
            vf[4*c] = vv4[c].x; vf[4*c+1] = vv4[c].y; vf[4*c+2] = vv4[c].z; vf[4*c+3] = vv4[c].w;
        }
        float ov[8];
#pragma unroll
        for (int i = 0; i < 8; ++i) {
            float qs = qv[i] * sl2e;
            float den = 0.f, num = 0.f;
#pragma unroll
            for (int j = 0; j < 16; ++j) {
                float e = __builtin_amdgcn_exp2f(qs * kf[j]);
                den += e;
                num = fmaf(e, vf[j], num);
            }
            ov[i] = num * __builtin_amdgcn_rcpf(den);
        }
        u32x4 o0 = {pkbf(ov[0], ov[1]), pkbf(ov[2], ov[3]),
                    pkbf(ov[4], ov[5]), pkbf(ov[6], ov[7])};
        *(u32x4*)&us_o[t * O_STRIDE + h * 16 + ih * 8] = o0;   // b128, A-layout
    };

    // out[half m] = o @ Wproj + b. Wave: 2 n-tiles x 1 m-tile.
    auto stage_c_half = [&](int m) {
        const int nb2 = wave * 2;
        bf16x8 af[4];
#pragma unroll
        for (int ks = 0; ks < 4; ++ks)
            af[ks] = *(const bf16x8*)&us_o[col * O_STRIDE + ks * 32 + quad * 8];
        f32x4 acc2[2];
#pragma unroll
        for (int n = 0; n < 2; ++n) {
            float b = bproj[(nb2 + n) * 16 + col];
            acc2[n] = (f32x4){b, b, b, b};
        }
#pragma unroll
        for (int ks = 0; ks < 4; ++ks) {
            bf16x8 bb[2];
#pragma unroll
            for (int n = 0; n < 2; ++n)
                bb[n] = *(const bf16x8*)&wprojT[((nb2 + n) * 16 + col) * 128 + ks * 32 + quad * 8];
#pragma unroll
            for (int n = 0; n < 2; ++n)
                acc2[n] = __builtin_amdgcn_mfma_f32_16x16x32_bf16(af[ks], bb[n], acc2[n], 0, 0, 0);
        }
#pragma unroll
        for (int n = 0; n < 2; ++n)
#pragma unroll
            for (int r = 0; r < 4; ++r) {
                long tt = base_tok + m * 16 + quad * 4 + r;
                out[tt * 128 + (nb2 + n) * 16 + col] = acc2[n][r];
            }
    };

    // ---- half-tile pipeline, 4 barriers
    write_qkv_half(0);
    __syncthreads();            // B1: qkv half0 visible
    stage_b_half();             // reads us_f half0, writes us_o half0
    __syncthreads();            // B2: o half0 visible; us_f half0 reads done
    write_qkv_half(1);          // overwrite us_f (overlaps stage C below)
    stage_c_half(0);            // reads us_o half0 + weights, stores out rows 0-15
    __syncthreads();            // B3: qkv half1 visible; us_o half0 reads done
    stage_b_half();             // reads us_f half1, writes us_o half1
    __syncthreads();            // B4: o half1 visible
    stage_c_half(1);
}

extern "C" void kernel_launch(void* const* d_in, const int* in_sizes, int n_in,
                              void* d_out, int out_size, void* d_ws, size_t ws_size,
                              hipStream_t stream) {
    const float* x     = (const float*)d_in[0];
    const float* wqkv  = (const float*)d_in[1];
    const float* bqkv  = (const float*)d_in[2];
    const float* wproj = (const float*)d_in[3];
    const float* bproj = (const float*)d_in[4];
    float* out = (float*)d_out;

    unsigned short* wqkvT  = (unsigned short*)d_ws;    // 384*128 bf16
    unsigned short* wprojT = wqkvT + 384 * 128;        // 128*128 bf16

    prep_weights<<<192, 256, 0, stream>>>(wqkv, wproj, wqkvT, wprojT);

    const int tokens = in_sizes[0] / 128;              // 65536
    fused_channel_attn<<<tokens / TILE_M, 256, 0, stream>>>(
        x, wqkvT, bqkv, wprojT, bproj, out);
}

// Round 2
// 138.661 us; speedup vs baseline: 1.1364x; 1.1364x over previous
//
#include <hip/hip_runtime.h>

// ChannelAttention fused kernel for MI355X (gfx950), round 6.
// B=4, L=16384, C=128, H=8, hd=16. Tokens M = 65536.
//
// R6 changes vs R5 (spill catastrophe: launch_bounds(256,5) gave ~102-reg
// unified budget, kernel needs ~120 -> scratch spills, FETCH 17->48MB,
// WRITE 33->94MB, dur regressed):
//   - __launch_bounds__(256,4): 128-reg budget, no spill. LDS (29184 B)
//     would allow 5 blocks/CU but VGPR caps 4 -> 50% occupancy cap
//     (vs R4's 37.5% LDS-capped).
//   - Stage A load+pack fused per (m,ks) so regalloc can trade load depth
//     for pressure instead of holding all 16 float4s live.
// Structure otherwise = R5 half-tile pipeline:
//   stage A: both m-tiles' qkv in regs (acc[2][6]), shared weight loads.
//   half-tile LDS: qkv fp32 16x388 (24832 B) + o bf16 16x136 (4352 B).
//   stage B: thread = (t, h, i-half), 8x16 exp2, 10x ds_read_b128.
//   stage C per half: wave = 2 n-tiles x 1 m-tile; half-1 qkv writes
//   overlap stage-C-half-0. 4 barriers.
// Math path identical to R4/R5 (fp32 LDS, bf16 MFMA operands, exp2 softmax).

typedef __attribute__((ext_vector_type(8))) short bf16x8;
typedef __attribute__((ext_vector_type(4))) float f32x4;
typedef __attribute__((ext_vector_type(4))) unsigned int u32x4;

#define TILE_M 32
#define HALF_M 16
#define QKV_STRIDE_F 388   // fp32 elems per token row (>=384; %8==4 -> 16B aligned rows, spread banks)
#define O_STRIDE 136       // bf16 elems per o row

__device__ __forceinline__ unsigned short f2bf(float f) {
    unsigned int u = __builtin_bit_cast(unsigned int, f);
    u += 0x8000u;                      // round half up (cheap, <=0.5 ulp + tie bias)
    return (unsigned short)(u >> 16);
}
// pack two floats -> packed bf16x2 (lo in low short) in 3 VALU ops
__device__ __forceinline__ unsigned int pkbf(float lo, float hi) {
    unsigned int a = __builtin_bit_cast(unsigned int, lo) + 0x8000u;
    unsigned int b = __builtin_bit_cast(unsigned int, hi) + 0x8000u;
    return __builtin_amdgcn_perm(b, a, 0x07060302u);  // {hi16(b),hi16(a)}
}

__global__ void prep_weights(const float* __restrict__ wqkv,
                             const float* __restrict__ wproj,
                             unsigned short* __restrict__ wqkvT,
                             unsigned short* __restrict__ wprojT) {
    int idx = blockIdx.x * 256 + threadIdx.x;
    if (idx < 384 * 128) {               // wqkvT[n][k] = bf16(wqkv[k][n])
        int n = idx >> 7, k = idx & 127;
        wqkvT[idx] = f2bf(wqkv[k * 384 + n]);
    }
    if (idx < 128 * 128) {               // wprojT[n][k] = bf16(wproj[k][n])
        int n = idx >> 7, k = idx & 127;
        wprojT[idx] = f2bf(wproj[k * 128 + n]);
    }
}

__global__ __launch_bounds__(256, 4) void fused_channel_attn(
    const float* __restrict__ x,
    const unsigned short* __restrict__ wqkvT,
    const float* __restrict__ bqkv,
    const unsigned short* __restrict__ wprojT,
    const float* __restrict__ bproj,
    float* __restrict__ out)
{
    __shared__ __align__(16) float us_f[HALF_M * QKV_STRIDE_F];        // 24832 B, half-tile qkv fp32
    __shared__ __align__(16) unsigned short us_o[HALF_M * O_STRIDE];   // 4352 B, half-tile o bf16

    const int tid  = threadIdx.x;
    const int lane = tid & 63;
    const int wave = tid >> 6;
    const int col  = lane & 15;   // MFMA C/D col == A row (m) == B col (n)
    const int quad = lane >> 4;
    const long base_tok = (long)blockIdx.x * TILE_M;

    const int nb = wave * 6;      // this wave's 6 qkv n-tiles (both m-tiles)

    // ---- stage A: x fragments, load+pack fused per (m,ks)
    bf16x8 afr[2][4];
#pragma unroll
    for (int m = 0; m < 2; ++m) {
        const float* xrow = x + (base_tok + m * 16 + col) * 128;
#pragma unroll
        for (int ks = 0; ks < 4; ++ks) {
            const float4* p = (const float4*)(xrow + ks * 32 + quad * 8);
            float4 f0 = p[0], f1 = p[1];
            u32x4 a = {pkbf(f0.x, f0.y), pkbf(f0.z, f0.w),
                       pkbf(f1.x, f1.y), pkbf(f1.z, f1.w)};
            afr[m][ks] = __builtin_bit_cast(bf16x8, a);
        }
    }

    // acc[m][j][r] = qkv[m*16 + quad*4 + r][(nb+j)*16 + col]; init = bias
    f32x4 acc[2][6];
#pragma unroll
    for (int j = 0; j < 6; ++j) {
        float b = bqkv[(nb + j) * 16 + col];
        acc[0][j] = (f32x4){b, b, b, b};
        acc[1][j] = (f32x4){b, b, b, b};
    }
#pragma unroll
    for (int ks = 0; ks < 4; ++ks) {
        bf16x8 bfr[6];                 // batched: 6 loads in flight
#pragma unroll
        for (int j = 0; j < 6; ++j)
            bfr[j] = *(const bf16x8*)&wqkvT[((nb + j) * 16 + col) * 128 + ks * 32 + quad * 8];
#pragma unroll
        for (int j = 0; j < 6; ++j) {  // each bfrag feeds 2 MFMAs
            acc[0][j] = __builtin_amdgcn_mfma_f32_16x16x32_bf16(afr[0][ks], bfr[j], acc[0][j], 0, 0, 0);
            acc[1][j] = __builtin_amdgcn_mfma_f32_16x16x32_bf16(afr[1][ks], bfr[j], acc[1][j], 0, 0, 0);
        }
    }

    // ---- stage B thread mapping: 16 tokens x 8 heads x 2 i-halves = 256
    const int t  = tid & 15;
    const int h  = (tid >> 4) & 7;
    const int ih = tid >> 7;
    const float sl2e = 0.08838834764831845f * 1.44269504088896340f; // scale*log2(e)

    // write one 16-token half of qkv -> LDS fp32 [tok][ch]
    auto write_qkv_half = [&](int m) {
#pragma unroll
        for (int j = 0; j < 6; ++j)
#pragma unroll
            for (int r = 0; r < 4; ++r)
                us_f[(quad * 4 + r) * QKV_STRIDE_F + (nb + j) * 16 + col] = acc[m][j][r];
    };

    // per-token-head channel attention on the current LDS half-tile
    auto stage_b_half = [&]() {
        const float* qkvrow = us_f + t * QKV_STRIDE_F + h * 16;
        float4 qv4[2], kv4[4], vv4[4];   // 10 ds_read_b128
        qv4[0] = ((const float4*)(qkvrow + ih * 8))[0];
        qv4[1] = ((const float4*)(qkvrow + ih * 8))[1];
#pragma unroll
        for (int c = 0; c < 4; ++c) {
            kv4[c] = ((const float4*)(qkvrow + 128))[c];
            vv4[c] = ((const float4*)(qkvrow + 256))[c];
        }
        float qv[8], kf[16], vf[16];
#pragma unroll
        for (int c = 0; c < 2; ++c) {
            qv[4*c] = qv4[c].x; qv[4*c+1] = qv4[c].y; qv[4*c+2] = qv4[c].z; qv[4*c+3] = qv4[c].w;
        }
#pragma unroll
        for (int c = 0; c < 4; ++c) {
            kf[4*c] = kv4[c].x; kf[4*c+1] = kv4[c].y; kf[4*c+2] = kv4[c].z; kf[4*c+3] = kv4[c].w;
            vf[4*c] = vv4[c].x; vf[4*c+1] = vv4[c].y; vf[4*c+2] = vv4[c].z; vf[4*c+3] = vv4[c].w;
        }
        float ov[8];
#pragma unroll
        for (int i = 0; i < 8; ++i) {
            float qs = qv[i] * sl2e;
            float den = 0.f, num = 0.f;
#pragma unroll
            for (int j = 0; j < 16; ++j) {
                float e = __builtin_amdgcn_exp2f(qs * kf[j]);
                den += e;
                num = fmaf(e, vf[j], num);
            }
            ov[i] = num * __builtin_amdgcn_rcpf(den);
        }
        u32x4 o0 = {pkbf(ov[0], ov[1]), pkbf(ov[2], ov[3]),
                    pkbf(ov[4], ov[5]), pkbf(ov[6], ov[7])};
        *(u32x4*)&us_o[t * O_STRIDE + h * 16 + ih * 8] = o0;   // b128, A-layout
    };

    // out[half m] = o @ Wproj + b. Wave: 2 n-tiles x 1 m-tile.
    auto stage_c_half = [&](int m) {
        const int nb2 = wave * 2;
        bf16x8 af[4];
#pragma unroll
        for (int ks = 0; ks < 4; ++ks)
            af[ks] = *(const bf16x8*)&us_o[col * O_STRIDE + ks * 32 + quad * 8];
        f32x4 acc2[2];
#pragma unroll
        for (int n = 0; n < 2; ++n) {
            float b = bproj[(nb2 + n) * 16 + col];
            acc2[n] = (f32x4){b, b, b, b};
        }
#pragma unroll
        for (int ks = 0; ks < 4; ++ks) {
            bf16x8 bb[2];
#pragma unroll
            for (int n = 0; n < 2; ++n)
                bb[n] = *(const bf16x8*)&wprojT[((nb2 + n) * 16 + col) * 128 + ks * 32 + quad * 8];
#pragma unroll
            for (int n = 0; n < 2; ++n)
                acc2[n] = __builtin_amdgcn_mfma_f32_16x16x32_bf16(af[ks], bb[n], acc2[n], 0, 0, 0);
        }
#pragma unroll
        for (int n = 0; n < 2; ++n)
#pragma unroll
            for (int r = 0; r < 4; ++r) {
                long tt = base_tok + m * 16 + quad * 4 + r;
                out[tt * 128 + (nb2 + n) * 16 + col] = acc2[n][r];
            }
    };

    // ---- half-tile pipeline, 4 barriers
    write_qkv_half(0);
    __syncthreads();            // B1: qkv half0 visible
    stage_b_half();             // reads us_f half0, writes us_o half0
    __syncthreads();            // B2: o half0 visible; us_f half0 reads done
    write_qkv_half(1);          // overwrite us_f (overlaps stage C below)
    stage_c_half(0);            // reads us_o half0 + weights, stores out rows 0-15
    __syncthreads();            // B3: qkv half1 visible; us_o half0 reads done
    stage_b_half();             // reads us_f half1, writes us_o half1
    __syncthreads();            // B4: o half1 visible
    stage_c_half(1);
}

extern "C" void kernel_launch(void* const* d_in, const int* in_sizes, int n_in,
                              void* d_out, int out_size, void* d_ws, size_t ws_size,
                              hipStream_t stream) {
    const float* x     = (const float*)d_in[0];
    const float* wqkv  = (const float*)d_in[1];
    const float* bqkv  = (const float*)d_in[2];
    const float* wproj = (const float*)d_in[3];
    const float* bproj = (const float*)d_in[4];
    float* out = (float*)d_out;

    unsigned short* wqkvT  = (unsigned short*)d_ws;    // 384*128 bf16
    unsigned short* wprojT = wqkvT + 384 * 128;        // 128*128 bf16

    prep_weights<<<192, 256, 0, stream>>>(wqkv, wproj, wqkvT, wprojT);

    const int tokens = in_sizes[0] / 128;              // 65536
    fused_channel_attn<<<tokens / TILE_M, 256, 0, stream>>>(
        x, wqkvT, bqkv, wprojT, bproj, out);
}

// Round 3
// 129.640 us; speedup vs baseline: 1.2155x; 1.0696x over previous
//
#include <hip/hip_runtime.h>

// ChannelAttention fused kernel for MI355X (gfx950), round 7.
// B=4, L=16384, C=128, H=8, hd=16. Tokens M = 65536.
//
// R7: head-aligned wave decomposition -> 1 barrier per block (was 4).
// R4/R6 post-mortem: per-block critical path (barrier + LDS round-trip
// latency, phase-locked across resident blocks) dominates; no pipe >35%.
// Barriers existed because head channels spanned waves. Now wave w computes
// qkv n-tiles of heads {2w, 2w+1}: tiles {2w,2w+1, 8+2w,9+2w, 16+2w,17+2w}.
// The qkv LDS transpose is wave-private: within-wave DS ops are in-order
// (compiler emits lgkmcnt for aliasing RAW), so NO barrier in the qkv path.
// Half-tile fp32 buffer (24832 B) reused by program order alone; half-1
// writes overlap half-0's exp2 burst. Single __syncthreads() before stage C
// (o A-frags span all heads). LDS 24832+8704 = 33536 B -> 4 blocks/CU.
// Stage B lanes: (t 0..15) x (hbit 0..1) x (ih 0..1); h = 2*wave+hbit.
// Math path identical to R4/R6 (fp32 LDS, bf16 MFMA operands, exp2 softmax).

typedef __attribute__((ext_vector_type(8))) short bf16x8;
typedef __attribute__((ext_vector_type(4))) float f32x4;
typedef __attribute__((ext_vector_type(4))) unsigned int u32x4;

#define TILE_M 32
#define HALF_M 16
#define QKV_STRIDE_F 388   // fp32 elems per token row (>=384; %8==4 -> 16B aligned rows, spread banks)
#define O_STRIDE 136       // bf16 elems per o row

__device__ __forceinline__ unsigned short f2bf(float f) {
    unsigned int u = __builtin_bit_cast(unsigned int, f);
    u += 0x8000u;                      // round half up (cheap, <=0.5 ulp + tie bias)
    return (unsigned short)(u >> 16);
}
// pack two floats -> packed bf16x2 (lo in low short) in 3 VALU ops
__device__ __forceinline__ unsigned int pkbf(float lo, float hi) {
    unsigned int a = __builtin_bit_cast(unsigned int, lo) + 0x8000u;
    unsigned int b = __builtin_bit_cast(unsigned int, hi) + 0x8000u;
    return __builtin_amdgcn_perm(b, a, 0x07060302u);  // {hi16(b),hi16(a)}
}

__global__ void prep_weights(const float* __restrict__ wqkv,
                             const float* __restrict__ wproj,
                             unsigned short* __restrict__ wqkvT,
                             unsigned short* __restrict__ wprojT) {
    int idx = blockIdx.x * 256 + threadIdx.x;
    if (idx < 384 * 128) {               // wqkvT[n][k] = bf16(wqkv[k][n])
        int n = idx >> 7, k = idx & 127;
        wqkvT[idx] = f2bf(wqkv[k * 384 + n]);
    }
    if (idx < 128 * 128) {               // wprojT[n][k] = bf16(wproj[k][n])
        int n = idx >> 7, k = idx & 127;
        wprojT[idx] = f2bf(wproj[k * 128 + n]);
    }
}

__global__ __launch_bounds__(256, 4) void fused_channel_attn(
    const float* __restrict__ x,
    const unsigned short* __restrict__ wqkvT,
    const float* __restrict__ bqkv,
    const unsigned short* __restrict__ wprojT,
    const float* __restrict__ bproj,
    float* __restrict__ out)
{
    __shared__ __align__(16) float us_f[HALF_M * QKV_STRIDE_F];        // 24832 B, half-tile qkv fp32
    __shared__ __align__(16) unsigned short us_o[TILE_M * O_STRIDE];   // 8704 B, full-tile o bf16

    const int tid  = threadIdx.x;
    const int lane = tid & 63;
    const int wave = tid >> 6;
    const int col  = lane & 15;   // MFMA C/D col == A row (m) == B col (n)
    const int quad = lane >> 4;
    const long base_tok = (long)blockIdx.x * TILE_M;

    // head-aligned n-tiles: wave w produces q,k,v channel tiles of heads 2w, 2w+1
    int ntile[6];
    ntile[0] = 2 * wave;      ntile[1] = 2 * wave + 1;
    ntile[2] = 8 + 2 * wave;  ntile[3] = 9 + 2 * wave;
    ntile[4] = 16 + 2 * wave; ntile[5] = 17 + 2 * wave;

    // ---- stage A: x fragments, load+pack fused per (m,ks)
    bf16x8 afr[2][4];
#pragma unroll
    for (int m = 0; m < 2; ++m) {
        const float* xrow = x + (base_tok + m * 16 + col) * 128;
#pragma unroll
        for (int ks = 0; ks < 4; ++ks) {
            const float4* p = (const float4*)(xrow + ks * 32 + quad * 8);
            float4 f0 = p[0], f1 = p[1];
            u32x4 a = {pkbf(f0.x, f0.y), pkbf(f0.z, f0.w),
                       pkbf(f1.x, f1.y), pkbf(f1.z, f1.w)};
            afr[m][ks] = __builtin_bit_cast(bf16x8, a);
        }
    }

    // acc[m][j][r] = qkv[m*16 + quad*4 + r][ntile[j]*16 + col]; init = bias
    f32x4 acc[2][6];
#pragma unroll
    for (int j = 0; j < 6; ++j) {
        float b = bqkv[ntile[j] * 16 + col];
        acc[0][j] = (f32x4){b, b, b, b};
        acc[1][j] = (f32x4){b, b, b, b};
    }
#pragma unroll
    for (int ks = 0; ks < 4; ++ks) {
        bf16x8 bfr[6];                 // batched: 6 loads in flight
#pragma unroll
        for (int j = 0; j < 6; ++j)
            bfr[j] = *(const bf16x8*)&wqkvT[(ntile[j] * 16 + col) * 128 + ks * 32 + quad * 8];
#pragma unroll
        for (int j = 0; j < 6; ++j) {  // each bfrag feeds 2 MFMAs
            acc[0][j] = __builtin_amdgcn_mfma_f32_16x16x32_bf16(afr[0][ks], bfr[j], acc[0][j], 0, 0, 0);
            acc[1][j] = __builtin_amdgcn_mfma_f32_16x16x32_bf16(afr[1][ks], bfr[j], acc[1][j], 0, 0, 0);
        }
    }

    // ---- stage B lane roles: (token, head-bit, i-half) within the wave
    const int t    = lane & 15;
    const int hbit = (lane >> 4) & 1;
    const int ih   = lane >> 5;
    const int h    = 2 * wave + hbit;           // head owned by this lane
    const float* qkvrow = us_f + t * QKV_STRIDE_F + h * 16;
    const float sl2e = 0.08838834764831845f * 1.44269504088896340f; // scale*log2(e)

    // write one 16-token half of this wave's qkv columns -> LDS fp32 [tok][ch]
    auto write_qkv_half = [&](int m) {
#pragma unroll
        for (int j = 0; j < 6; ++j)
#pragma unroll
            for (int r = 0; r < 4; ++r)
                us_f[(quad * 4 + r) * QKV_STRIDE_F + ntile[j] * 16 + col] = acc[m][j][r];
    };

    float4 qv4[2], kv4[4], vv4[4];   // 10 ds_read_b128 per half
    auto read_half = [&]() {
        qv4[0] = ((const float4*)(qkvrow + ih * 8))[0];
        qv4[1] = ((const float4*)(qkvrow + ih * 8))[1];
#pragma unroll
        for (int c = 0; c < 4; ++c) {
            kv4[c] = ((const float4*)(qkvrow + 128))[c];
            vv4[c] = ((const float4*)(qkvrow + 256))[c];
        }
    };

    auto compute_attn = [&](int mhalf) {
        float qv[8], kf[16], vf[16];
#pragma unroll
        for (int c = 0; c < 2; ++c) {
            qv[4*c] = qv4[c].x; qv[4*c+1] = qv4[c].y; qv[4*c+2] = qv4[c].z; qv[4*c+3] = qv4[c].w;
        }
#pragma unroll
        for (int c = 0; c < 4; ++c) {
            kf[4*c] = kv4[c].x; kf[4*c+1] = kv4[c].y; kf[4*c+2] = kv4[c].z; kf[4*c+3] = kv4[c].w;
            vf[4*c] = vv4[c].x; vf[4*c+1] = vv4[c].y; vf[4*c+2] = vv4[c].z; vf[4*c+3] = vv4[c].w;
        }
        float ov[8];
#pragma unroll
        for (int i = 0; i < 8; ++i) {
            float qs = qv[i] * sl2e;
            float den = 0.f, num = 0.f;
#pragma unroll
            for (int j = 0; j < 16; ++j) {
                float e = __builtin_amdgcn_exp2f(qs * kf[j]);
                den += e;
                num = fmaf(e, vf[j], num);
            }
            ov[i] = num * __builtin_amdgcn_rcpf(den);
        }
        u32x4 o0 = {pkbf(ov[0], ov[1]), pkbf(ov[2], ov[3]),
                    pkbf(ov[4], ov[5]), pkbf(ov[6], ov[7])};
        *(u32x4*)&us_o[(mhalf * 16 + t) * O_STRIDE + h * 16 + ih * 8] = o0;  // b128, A-layout
    };

    // ---- barrier-free wave-private qkv pipeline
    write_qkv_half(0);     // 24 ds_write_b32 (wave-owned columns only)
    read_half();           // RAW same wave: compiler lgkmcnt, in-order DS
    write_qkv_half(1);     // anti-dep on reads above: program order keeps safe;
                           // latency hides under half-0 exp2 burst below
    compute_attn(0);       // pure compute + 1 b128 o-write
    read_half();           // RAW on half-1 writes (same wave)
    compute_attn(1);

    __syncthreads();       // the ONE barrier: o (all heads/waves) -> stage C

    // ---- stage C: out = o @ Wproj + b. Wave: 2 n-tiles x 2 m-tiles.
    const int nb2 = wave * 2;
#pragma unroll
    for (int m = 0; m < 2; ++m) {
        bf16x8 af[4];
#pragma unroll
        for (int ks = 0; ks < 4; ++ks)
            af[ks] = *(const bf16x8*)&us_o[(m * 16 + col) * O_STRIDE + ks * 32 + quad * 8];
        f32x4 acc2[2];
#pragma unroll
        for (int n = 0; n < 2; ++n) {
            float b = bproj[(nb2 + n) * 16 + col];
            acc2[n] = (f32x4){b, b, b, b};
        }
#pragma unroll
        for (int ks = 0; ks < 4; ++ks) {
            bf16x8 bb[2];
#pragma unroll
            for (int n = 0; n < 2; ++n)
                bb[n] = *(const bf16x8*)&wprojT[((nb2 + n) * 16 + col) * 128 + ks * 32 + quad * 8];
#pragma unroll
            for (int n = 0; n < 2; ++n)
                acc2[n] = __builtin_amdgcn_mfma_f32_16x16x32_bf16(af[ks], bb[n], acc2[n], 0, 0, 0);
        }
#pragma unroll
        for (int n = 0; n < 2; ++n)
#pragma unroll
            for (int r = 0; r < 4; ++r) {
                long tt = base_tok + m * 16 + quad * 4 + r;
                out[tt * 128 + (nb2 + n) * 16 + col] = acc2[n][r];
            }
    }
}

extern "C" void kernel_launch(void* const* d_in, const int* in_sizes, int n_in,
                              void* d_out, int out_size, void* d_ws, size_t ws_size,
                              hipStream_t stream) {
    const float* x     = (const float*)d_in[0];
    const float* wqkv  = (const float*)d_in[1];
    const float* bqkv  = (const float*)d_in[2];
    const float* wproj = (const float*)d_in[3];
    const float* bproj = (const float*)d_in[4];
    float* out = (float*)d_out;

    unsigned short* wqkvT  = (unsigned short*)d_ws;    // 384*128 bf16
    unsigned short* wprojT = wqkvT + 384 * 128;        // 128*128 bf16

    prep_weights<<<192, 256, 0, stream>>>(wqkv, wproj, wqkvT, wprojT);

    const int tokens = in_sizes[0] / 128;              // 65536
    fused_channel_attn<<<tokens / TILE_M, 256, 0, stream>>>(
        x, wqkvT, bqkv, wprojT, bproj, out);
}